// Round 1
// baseline (98.208 us; speedup 1.0000x reference)
//
#include <hip/hip_runtime.h>
#include <hip/hip_bf16.h>

// TSM temporal shift + 1x1 conv (256->256) fused as bf16 MFMA GEMM.
// x: [128, 256, 28, 28] f32, w: [256, 256] f32, out: [128, 256, 28, 28] f32.
// Per frame n: out[o,p] = sum_c W[o,c] * Y[c,p],
//   Y[c,p] = x[n-1,c,p] (c<32, t>0), x[n+1,c,p] (32<=c<64, t<7), x[n,c,p] else
//   (zeros at clip edges), t = n % 8.

#define N_FRAMES 8
#define C_DIM    256
#define HW       784
#define P_TILE   112
#define FOLD     32
#define LDS_STRIDE (C_DIM + 8)   // 264 bf16 -> 528B row stride (33*16B, breaks bank conflicts)

using bf16x8 = __attribute__((ext_vector_type(8))) short;
using f32x4  = __attribute__((ext_vector_type(4))) float;

static __device__ __forceinline__ unsigned int pk2(float lo, float hi) {
    union { __hip_bfloat162 h; unsigned int u; } cv;
    cv.h = __float22bfloat162_rn(make_float2(lo, hi));
    return cv.u;
}

__global__ __launch_bounds__(256, 2)
void tsm_pw_gemm(const float* __restrict__ x,
                 const float* __restrict__ w,
                 float* __restrict__ out) {
    // bf16 Y tile, layout [p][c], p=0..111, c=0..255 (stride 264)
    __shared__ __align__(16) unsigned short ylds[P_TILE * LDS_STRIDE];

    const int n    = blockIdx.x;           // frame 0..127
    const int tile = blockIdx.y;           // 0..6
    const int p0   = tile * P_TILE;
    const int tid  = threadIdx.x;
    const int tf   = n & (N_FRAMES - 1);   // frame index within clip

    // ---------------- stage shifted Y into LDS (transposed, bf16) --------
    {
        const int u    = tid & 127;        // channel pair index: c0 = 2u, 2u+1
        const int half = tid >> 7;         // pixel half (56 pixels each)
        const int c0   = u * 2;
        int  nsrc;
        bool valid;
        if (c0 < FOLD)            { nsrc = n - 1; valid = (tf > 0); }
        else if (c0 < 2 * FOLD)   { nsrc = n + 1; valid = (tf < N_FRAMES - 1); }
        else                      { nsrc = n;     valid = true; }
        const int ns = valid ? nsrc : n;   // keep pointer in-range; loads predicated
        const float* r0 = x + ((size_t)ns * C_DIM + c0) * HW + p0 + half * 56;
        const float* r1 = r0 + HW;
        const int pbase = half * 56;
        #pragma unroll
        for (int pg = 0; pg < 14; ++pg) {
            f32x4 a = {0.f, 0.f, 0.f, 0.f};
            f32x4 b = {0.f, 0.f, 0.f, 0.f};
            if (valid) {
                a = *(const f32x4*)(r0 + pg * 4);
                b = *(const f32x4*)(r1 + pg * 4);
            }
            #pragma unroll
            for (int i = 0; i < 4; ++i) {
                const int p = pbase + pg * 4 + i;
                // c0 even -> 4B aligned; low half = c0, high half = c0+1
                *(unsigned int*)&ylds[p * LDS_STRIDE + c0] = pk2(a[i], b[i]);
            }
        }
    }
    __syncthreads();

    // ---------------- MFMA: D[o,p] = W[o,:] x Y[:,p] ----------------------
    const int lane = tid & 63;
    const int wv   = tid >> 6;     // wave -> 64 out-channel block
    const int g    = lane >> 4;    // k-group (0..3)
    const int ol   = lane & 15;    // row/col within fragment

    f32x4 acc[4][7];
    #pragma unroll
    for (int m = 0; m < 4; ++m)
        #pragma unroll
        for (int nn = 0; nn < 7; ++nn)
            acc[m][nn] = f32x4{0.f, 0.f, 0.f, 0.f};

    for (int kk = 0; kk < 8; ++kk) {
        const int c = kk * 32 + g * 8;   // k = G*8 + j, same bijection for A and B
        bf16x8 af[4];
        #pragma unroll
        for (int m = 0; m < 4; ++m) {
            const int o = wv * 64 + m * 16 + ol;     // A row on lane&15
            const float* wp = w + (size_t)o * C_DIM + c;
            f32x4 w0 = *(const f32x4*)wp;
            f32x4 w1 = *(const f32x4*)(wp + 4);
            union { bf16x8 v; unsigned int u4[4]; } cv;
            cv.u4[0] = pk2(w0[0], w0[1]);
            cv.u4[1] = pk2(w0[2], w0[3]);
            cv.u4[2] = pk2(w1[0], w1[1]);
            cv.u4[3] = pk2(w1[2], w1[3]);
            af[m] = cv.v;
        }
        #pragma unroll
        for (int nn = 0; nn < 7; ++nn) {
            // B col on lane&15 (pixel), 8 consecutive c -> ds_read_b128
            const bf16x8 bfrag =
                *(const bf16x8*)&ylds[(nn * 16 + ol) * LDS_STRIDE + c];
            #pragma unroll
            for (int m = 0; m < 4; ++m)
                acc[m][nn] = __builtin_amdgcn_mfma_f32_16x16x32_bf16(
                    af[m], bfrag, acc[m][nn], 0, 0, 0);
        }
    }

    // ---------------- epilogue: C/D col=lane&15 (p), row=(lane>>4)*4+r (o) -
    const size_t outbase = (size_t)n * C_DIM * HW + p0 + ol;
    #pragma unroll
    for (int m = 0; m < 4; ++m) {
        #pragma unroll
        for (int r = 0; r < 4; ++r) {
            const int o = wv * 64 + m * 16 + g * 4 + r;
            float* orow = out + outbase + (size_t)o * HW;
            #pragma unroll
            for (int nn = 0; nn < 7; ++nn)
                orow[nn * 16] = acc[m][nn][r];
        }
    }
}

extern "C" void kernel_launch(void* const* d_in, const int* in_sizes, int n_in,
                              void* d_out, int out_size, void* d_ws, size_t ws_size,
                              hipStream_t stream) {
    const float* x = (const float*)d_in[0];
    const float* w = (const float*)d_in[1];
    float* out     = (float*)d_out;
    dim3 grid(128, 7, 1);
    tsm_pw_gemm<<<grid, dim3(256, 1, 1), 0, stream>>>(x, w, out);
}

// Round 2
// 57.349 us; speedup vs baseline: 1.7125x; 1.7125x over previous
//
#include <hip/hip_runtime.h>
#include <hip/hip_bf16.h>

// TSM temporal shift + 1x1 conv (256->256) fused as bf16 MFMA GEMM.
// x: [128, 256, 28, 28] f32, w: [256, 256] f32, out: [128, 256, 28, 28] f32.
// out[n,o,p] = sum_c W[o,c] * Y[c,p],
//   Y[c,p] = x[n-1,c,p] (c<32, t>0), x[n+1,c,p] (32<=c<64, t<7), x[n,c,p] else
//   (zeros at clip edges), t = n % 8.
//
// R2: latency-bound fix. Coalesced flat staging loads (1KB/wave-instr),
// load/write split for deep vmcnt pipelining, 8 waves/block @ 2 blocks/CU
// (50% occupancy cap), XOR column swizzle on the transposed LDS tile.

#define N_FRAMES 8
#define C_DIM    256
#define HW       784
#define P_TILE   112
#define FOLD     32
#define LDS_STRIDE 264   // halfwords per pixel row; 528B = 33*16B

using bf16x8 = __attribute__((ext_vector_type(8))) short;
using f32x4  = __attribute__((ext_vector_type(4))) float;

static __device__ __forceinline__ unsigned int pk2(float lo, float hi) {
    union { __hip_bfloat162 h; unsigned int u; } cv;
    cv.h = __float22bfloat162_rn(make_float2(lo, hi));
    return cv.u;
}

static __device__ __forceinline__ unsigned short bf1(float v) {
    union { __hip_bfloat16 h; unsigned short u; } cv;
    cv.h = __float2bfloat16(v);
    return cv.u;
}

__global__ __launch_bounds__(512, 4)   // 4 waves/SIMD -> 2 blocks/CU
void tsm_pw_gemm(const float* __restrict__ x,
                 const float* __restrict__ w,
                 float* __restrict__ out) {
    // bf16 Y tile, layout [p][c'], c' = c ^ ((p>>2 & 7)<<3)  (16B-chunk XOR swizzle)
    __shared__ __align__(16) unsigned short ylds[P_TILE * LDS_STRIDE];

    const int n    = blockIdx.x;           // frame
    const int tile = blockIdx.y;           // 0..6
    const int p0   = tile * P_TILE;
    const int tid  = threadIdx.x;
    const int tf   = n & (N_FRAMES - 1);

    // ------------- staging: coalesced f32x4 loads, all issued up front -----
    // 7168 vec4 = 256 c * 28 vec-per-row; vidx = tid + i*512, c = vidx/28.
    f32x4 vals[14];
    int   cs[14], pvs[14];
    #pragma unroll
    for (int i = 0; i < 14; ++i) {
        const int vidx = tid + i * 512;
        const int c  = vidx / 28;          // const div -> magic mul
        const int pv = vidx - c * 28;
        cs[i] = c; pvs[i] = pv;
        int  nsrc;
        bool valid;
        if (c < FOLD)           { nsrc = n - 1; valid = (tf > 0); }
        else if (c < 2 * FOLD)  { nsrc = n + 1; valid = (tf < N_FRAMES - 1); }
        else                    { nsrc = n;     valid = true; }
        const float* src = x + ((size_t)(valid ? nsrc : n) * C_DIM + c) * HW
                             + p0 + pv * 4;
        f32x4 v = {0.f, 0.f, 0.f, 0.f};
        if (valid) v = *(const f32x4*)src;
        vals[i] = v;
    }
    #pragma unroll
    for (int i = 0; i < 14; ++i) {
        const int c  = cs[i];
        const int pv = pvs[i];
        const int cc = c ^ ((pv & 7) << 3);          // swizzle: p>>2 == pv
        const int rb = pv * 4 * LDS_STRIDE + cc;
        ylds[rb                 ] = bf1(vals[i][0]);
        ylds[rb + 1 * LDS_STRIDE] = bf1(vals[i][1]);
        ylds[rb + 2 * LDS_STRIDE] = bf1(vals[i][2]);
        ylds[rb + 3 * LDS_STRIDE] = bf1(vals[i][3]);
    }
    __syncthreads();

    // ------------- MFMA: D[o,p] = W[o,:] x Y[:,p] --------------------------
    const int lane = tid & 63;
    const int wv   = tid >> 6;     // wave -> 32 out-channel block
    const int g    = lane >> 4;    // k-group
    const int ol   = lane & 15;

    f32x4 acc[2][7];
    #pragma unroll
    for (int m = 0; m < 2; ++m)
        #pragma unroll
        for (int nn = 0; nn < 7; ++nn)
            acc[m][nn] = f32x4{0.f, 0.f, 0.f, 0.f};

    for (int kk = 0; kk < 8; ++kk) {
        const int c = kk * 32 + g * 8;           // k = g*8 + j for A and B
        bf16x8 af[2];
        #pragma unroll
        for (int m = 0; m < 2; ++m) {
            const int o = wv * 32 + m * 16 + ol; // A row on lane&15
            const float* wp = w + (size_t)o * C_DIM + c;
            f32x4 w0 = *(const f32x4*)wp;
            f32x4 w1 = *(const f32x4*)(wp + 4);
            union { bf16x8 v; unsigned int u4[4]; } cv;
            cv.u4[0] = pk2(w0[0], w0[1]);
            cv.u4[1] = pk2(w0[2], w0[3]);
            cv.u4[2] = pk2(w1[0], w1[1]);
            cv.u4[3] = pk2(w1[2], w1[3]);
            af[m] = cv.v;
        }
        #pragma unroll
        for (int nn = 0; nn < 7; ++nn) {
            const int p  = nn * 16 + ol;         // B col = pixel on lane&15
            const int cc = c ^ (((p >> 2) & 7) << 3);
            const bf16x8 bfrag = *(const bf16x8*)&ylds[p * LDS_STRIDE + cc];
            #pragma unroll
            for (int m = 0; m < 2; ++m)
                acc[m][nn] = __builtin_amdgcn_mfma_f32_16x16x32_bf16(
                    af[m], bfrag, acc[m][nn], 0, 0, 0);
        }
    }

    // ------------- epilogue: C/D col=lane&15 (p), row=(lane>>4)*4+r (o) ----
    const size_t outbase = (size_t)n * C_DIM * HW + p0 + ol;
    #pragma unroll
    for (int m = 0; m < 2; ++m) {
        #pragma unroll
        for (int r = 0; r < 4; ++r) {
            const int o = wv * 32 + m * 16 + g * 4 + r;
            float* orow = out + outbase + (size_t)o * HW;
            #pragma unroll
            for (int nn = 0; nn < 7; ++nn)
                orow[nn * 16] = acc[m][nn][r];
        }
    }
}

extern "C" void kernel_launch(void* const* d_in, const int* in_sizes, int n_in,
                              void* d_out, int out_size, void* d_ws, size_t ws_size,
                              hipStream_t stream) {
    const float* x = (const float*)d_in[0];
    const float* w = (const float*)d_in[1];
    float* out     = (float*)d_out;
    dim3 grid(128, 7, 1);
    tsm_pw_gemm<<<grid, dim3(512, 1, 1), 0, stream>>>(x, w, out);
}

// Round 3
// 52.322 us; speedup vs baseline: 1.8770x; 1.0961x over previous
//
#include <hip/hip_runtime.h>
#include <hip/hip_bf16.h>

// TSM temporal shift + 1x1 conv (256->256) fused as bf16 MFMA GEMM.
// x: [128, 256, 28, 28] f32, w: [256, 256] f32, out: [128, 256, 28, 28] f32.
// out[n,o,p] = sum_c W[o,c] * Y[c,p],
//   Y[c,p] = x[n-1,c,p] (c<32, t>0), x[n+1,c,p] (32<=c<64, t<7), x[n,c,p] else.
//
// R3: (1) sched_barrier(0) pins all 14 staging loads before the convert/write
//     loop (R2's VGPR=64 showed the compiler re-fused them -> serial latency);
// (2) W pre-converted to bf16 in d_ws by a tiny kernel -> A-frag is one 16B
//     L2-hit load, no pk2 chain in the MFMA loop;
// (3) channel-pair staging -> 28 ds_write_b32 instead of 56 ds_write_b16.

#define N_FRAMES 8
#define C_DIM    256
#define HW       784
#define P_TILE   112
#define FOLD     32
#define LDS_STRIDE 264   // halfwords per pixel row; 528B = 33*16B

using bf16x8 = __attribute__((ext_vector_type(8))) short;
using f32x4  = __attribute__((ext_vector_type(4))) float;

static __device__ __forceinline__ unsigned int pk2(float lo, float hi) {
    union { __hip_bfloat162 h; unsigned int u; } cv;
    cv.h = __float22bfloat162_rn(make_float2(lo, hi));
    return cv.u;
}

// ---- W f32 -> bf16 row-major (one-shot, 256KB read / 128KB write) ----------
__global__ void wconv(const float* __restrict__ w, unsigned short* __restrict__ wb) {
    const int i = (blockIdx.x * 256 + threadIdx.x) * 4;   // 16384 threads * 4
    f32x4 v = *(const f32x4*)(w + i);
    unsigned int lo = pk2(v[0], v[1]);
    unsigned int hi = pk2(v[2], v[3]);
    *(uint2*)(wb + i) = make_uint2(lo, hi);
}

template <bool USE_WB>
__global__ __launch_bounds__(512, 4)   // <=128 VGPR -> 4 waves/SIMD, 2 blocks/CU
void tsm_pw_gemm(const float* __restrict__ x,
                 const float* __restrict__ w,
                 const unsigned short* __restrict__ wb,
                 float* __restrict__ out) {
    // bf16 Y tile, layout [p][c'], c' = c ^ (((p>>2)&7)<<3)
    __shared__ __align__(16) unsigned short ylds[P_TILE * LDS_STRIDE];

    const int n    = blockIdx.x;
    const int tile = blockIdx.y;
    const int p0   = tile * P_TILE;
    const int tid  = threadIdx.x;
    const int tf   = n & (N_FRAMES - 1);

    // ------------- staging: channel-pair loads, all issued before any write
    // (c-pair, pv) space = 128*28 = 3584 = 7*512
    f32x4 v0[7], v1[7];
    int   cps[7], pvs[7];
    #pragma unroll
    for (int i = 0; i < 7; ++i) {
        const int idx = tid + i * 512;
        const int cp  = idx / 28;          // magic-mul
        const int pv  = idx - cp * 28;
        cps[i] = cp; pvs[i] = pv;
        const int c0 = cp * 2;
        int  nsrc;
        bool valid;
        if (c0 < FOLD)           { nsrc = n - 1; valid = (tf > 0); }
        else if (c0 < 2 * FOLD)  { nsrc = n + 1; valid = (tf < N_FRAMES - 1); }
        else                     { nsrc = n;     valid = true; }
        const float* src = x + ((size_t)(valid ? nsrc : n) * C_DIM + c0) * HW
                             + p0 + pv * 4;
        f32x4 a = {0.f, 0.f, 0.f, 0.f};
        f32x4 b = {0.f, 0.f, 0.f, 0.f};
        if (valid) {
            a = *(const f32x4*)src;
            b = *(const f32x4*)(src + HW);
        }
        v0[i] = a; v1[i] = b;
    }
    __builtin_amdgcn_sched_barrier(0);     // loads stay issued above this line
    #pragma unroll
    for (int i = 0; i < 7; ++i) {
        const int c0 = cps[i] * 2;
        const int pv = pvs[i];
        const int cc = c0 ^ ((pv & 7) << 3);        // p>>2 == pv for rows below
        const int rb = pv * 4 * LDS_STRIDE + cc;    // cc even -> 4B aligned
        #pragma unroll
        for (int r = 0; r < 4; ++r)
            *(unsigned int*)&ylds[rb + r * LDS_STRIDE] = pk2(v0[i][r], v1[i][r]);
    }
    __syncthreads();

    // ------------- MFMA: D[o,p] = W[o,:] x Y[:,p] --------------------------
    const int lane = tid & 63;
    const int wv   = tid >> 6;     // wave -> 32 out-channel block
    const int g    = lane >> 4;
    const int ol   = lane & 15;

    f32x4 acc[2][7];
    #pragma unroll
    for (int m = 0; m < 2; ++m)
        #pragma unroll
        for (int nn = 0; nn < 7; ++nn)
            acc[m][nn] = f32x4{0.f, 0.f, 0.f, 0.f};

    #pragma unroll
    for (int kk = 0; kk < 8; ++kk) {
        const int c = kk * 32 + g * 8;           // k = g*8 + j for A and B
        bf16x8 af[2];
        #pragma unroll
        for (int m = 0; m < 2; ++m) {
            const int o = wv * 32 + m * 16 + ol; // A row on lane&15
            if (USE_WB) {
                af[m] = *(const bf16x8*)&wb[(size_t)o * C_DIM + c];
            } else {
                const float* wp = w + (size_t)o * C_DIM + c;
                f32x4 w0 = *(const f32x4*)wp;
                f32x4 w1 = *(const f32x4*)(wp + 4);
                union { bf16x8 v; unsigned int u4[4]; } cv;
                cv.u4[0] = pk2(w0[0], w0[1]);
                cv.u4[1] = pk2(w0[2], w0[3]);
                cv.u4[2] = pk2(w1[0], w1[1]);
                cv.u4[3] = pk2(w1[2], w1[3]);
                af[m] = cv.v;
            }
        }
        #pragma unroll
        for (int nn = 0; nn < 7; ++nn) {
            const int p  = nn * 16 + ol;
            const int cc = c ^ (((p >> 2) & 7) << 3);
            const bf16x8 bfrag = *(const bf16x8*)&ylds[p * LDS_STRIDE + cc];
            #pragma unroll
            for (int m = 0; m < 2; ++m)
                acc[m][nn] = __builtin_amdgcn_mfma_f32_16x16x32_bf16(
                    af[m], bfrag, acc[m][nn], 0, 0, 0);
        }
    }

    // ------------- epilogue ------------------------------------------------
    const size_t outbase = (size_t)n * C_DIM * HW + p0 + ol;
    #pragma unroll
    for (int m = 0; m < 2; ++m) {
        #pragma unroll
        for (int r = 0; r < 4; ++r) {
            const int o = wv * 32 + m * 16 + g * 4 + r;
            float* orow = out + outbase + (size_t)o * HW;
            #pragma unroll
            for (int nn = 0; nn < 7; ++nn)
                orow[nn * 16] = acc[m][nn][r];
        }
    }
}

extern "C" void kernel_launch(void* const* d_in, const int* in_sizes, int n_in,
                              void* d_out, int out_size, void* d_ws, size_t ws_size,
                              hipStream_t stream) {
    const float* x = (const float*)d_in[0];
    const float* w = (const float*)d_in[1];
    float* out     = (float*)d_out;
    dim3 grid(128, 7, 1);
    if (ws_size >= (size_t)C_DIM * C_DIM * sizeof(unsigned short)) {
        unsigned short* wb = (unsigned short*)d_ws;
        wconv<<<64, 256, 0, stream>>>(w, wb);
        tsm_pw_gemm<true><<<grid, dim3(512, 1, 1), 0, stream>>>(x, w, wb, out);
    } else {
        tsm_pw_gemm<false><<<grid, dim3(512, 1, 1), 0, stream>>>(x, w, nullptr, out);
    }
}